// Round 1
// baseline (54259.351 us; speedup 1.0000x reference)
//
#include <hip/hip_runtime.h>

// 2-layer LSTM (H=128) + FC, batch-parallel persistent kernel.
// Design: thread t (of 512) owns gate-row t of w_hh0, w_ih1, w_hh1, held
// STATIONARY in VGPRs as fp16 (3 * 64 half2 = 192 VGPRs). Hidden states h1/h2
// live in LDS as fp16 (broadcast-read via ds_read_b128), cell states c1/c2 in
// fp32 registers of the update-phase thread (fixed (row,j) <-> thread map).
// fp32 accumulation everywhere via v_dot2_f32_f16. No weight re-streaming:
// steady-state global traffic is just 20 x-floats per block per step.
// Block = 512 threads (8 waves), 4 batch rows; grid = 256 = 1 block/CU.
// __launch_bounds__(512,2): 2 waves/EU -> 256-VGPR cap, exactly fills the CU.

#define SEQ   512
#define BATCH 1024
#define HID   128
#define GATES (4 * HID)
#define ROWS  4
#define NTHR  512
#define NBLK  (BATCH / ROWS)

typedef _Float16 half_t;
typedef __attribute__((ext_vector_type(2))) _Float16 half2_t;
typedef __attribute__((ext_vector_type(8))) _Float16 half8_t;

__device__ __forceinline__ float dot2f(half2_t a, half2_t b, float c) {
#if __has_builtin(__builtin_amdgcn_fdot2)
    return __builtin_amdgcn_fdot2(a, b, c, false);
#else
    return fmaf((float)a[0], (float)b[0], fmaf((float)a[1], (float)b[1], c));
#endif
}

__device__ __forceinline__ float sigm(float x) {
    return 1.0f / (1.0f + __expf(-x));
}
__device__ __forceinline__ float tanh_fast(float x) {
    // tanh(x) = (e^{2x}-1)/(e^{2x}+1); saturates correctly for |x| large.
    float e = __expf(2.0f * x);
    return 1.0f - 2.0f / (e + 1.0f);
}

__global__ void __launch_bounds__(NTHR, 2)
lstm2_fused(const float* __restrict__ x,
            const float* __restrict__ w_ih0, const float* __restrict__ w_hh0,
            const float* __restrict__ b_ih0, const float* __restrict__ b_hh0,
            const float* __restrict__ w_ih1, const float* __restrict__ w_hh1,
            const float* __restrict__ b_ih1, const float* __restrict__ b_hh1,
            const float* __restrict__ fc_w,  const float* __restrict__ fc_b,
            float* __restrict__ out)
{
    const int t    = threadIdx.x;          // gate id 0..511 (PyTorch order i,f,g,o)
    const int row0 = blockIdx.x * ROWS;    // batch rows handled by this block

    __shared__ __align__(16) half_t h1s[ROWS][HID];
    __shared__ __align__(16) half_t h2s[ROWS][HID];
    __shared__ float gbuf[ROWS][GATES];    // pre-activation gates, fp32
    __shared__ float xs[ROWS][5];          // current-step x slice
    __shared__ float wpart[NTHR / 64];     // epilogue wave partials

    // ---- load stationary weights: fp32 -> fp16 (RTN), packed half2 in VGPRs ----
    half2_t whh0[HID / 2], wih1[HID / 2], whh1[HID / 2];
#pragma unroll
    for (int k = 0; k < HID / 2; ++k) {
        float2 a = *(const float2*)(w_hh0 + (size_t)t * HID + 2 * k);
        half2_t v; v[0] = (half_t)a.x; v[1] = (half_t)a.y; whh0[k] = v;
    }
#pragma unroll
    for (int k = 0; k < HID / 2; ++k) {
        float2 a = *(const float2*)(w_ih1 + (size_t)t * HID + 2 * k);
        half2_t v; v[0] = (half_t)a.x; v[1] = (half_t)a.y; wih1[k] = v;
    }
#pragma unroll
    for (int k = 0; k < HID / 2; ++k) {
        float2 a = *(const float2*)(w_hh1 + (size_t)t * HID + 2 * k);
        half2_t v; v[0] = (half_t)a.x; v[1] = (half_t)a.y; whh1[k] = v;
    }
    float wx[5];                           // layer-0 input weights, fp32 (tiny)
#pragma unroll
    for (int d = 0; d < 5; ++d) wx[d] = w_ih0[t * 5 + d];
    const float bias0 = b_ih0[t] + b_hh0[t];
    const float bias1 = b_ih1[t] + b_hh1[t];

    // update-phase mapping: thread <-> (row, hidden j), fixed across steps
    const int ur = t >> 7;
    const int uj = t & (HID - 1);
    float c1 = 0.0f, c2 = 0.0f, h2v = 0.0f;

    h1s[ur][uj] = (half_t)0.0f;
    h2s[ur][uj] = (half_t)0.0f;
    if (t < ROWS * 5)
        xs[t / 5][t % 5] = x[(size_t)(row0 + t / 5) * (SEQ * 5) + (t % 5)];
    __syncthreads();

    for (int s = 0; s < SEQ; ++s) {
        // ---- phase 1: layer-0 gates: g = bias0 + w_ih0 . x_t + w_hh0 . h1 ----
        float acc[ROWS];
#pragma unroll
        for (int r = 0; r < ROWS; ++r) {
            float a = bias0;
#pragma unroll
            for (int d = 0; d < 5; ++d) a = fmaf(wx[d], xs[r][d], a);
            acc[r] = a;
        }
#pragma unroll
        for (int r = 0; r < ROWS; ++r) {
            const half8_t* hp = (const half8_t*)(&h1s[r][0]);
#pragma unroll
            for (int k = 0; k < HID / 8; ++k) {
                half8_t hv = hp[k];   // wave-uniform ds_read_b128 (broadcast)
                acc[r] = dot2f(__builtin_shufflevector(hv, hv, 0, 1), whh0[4 * k + 0], acc[r]);
                acc[r] = dot2f(__builtin_shufflevector(hv, hv, 2, 3), whh0[4 * k + 1], acc[r]);
                acc[r] = dot2f(__builtin_shufflevector(hv, hv, 4, 5), whh0[4 * k + 2], acc[r]);
                acc[r] = dot2f(__builtin_shufflevector(hv, hv, 6, 7), whh0[4 * k + 3], acc[r]);
            }
        }
#pragma unroll
        for (int r = 0; r < ROWS; ++r) gbuf[r][t] = acc[r];
        __syncthreads();

        // ---- phase 2: layer-0 pointwise update (thread = (ur,uj)) ----
        {
            float gi = gbuf[ur][uj];
            float gf = gbuf[ur][HID + uj];
            float gg = gbuf[ur][2 * HID + uj];
            float go = gbuf[ur][3 * HID + uj];
            float iv = sigm(gi), fv = sigm(gf), gv = tanh_fast(gg), ov = sigm(go);
            c1 = fmaf(fv, c1, iv * gv);
            h1s[ur][uj] = (half_t)(ov * tanh_fast(c1));
        }
        __syncthreads();

        // ---- phase 3: layer-1 gates: g = bias1 + w_ih1 . h1_t + w_hh1 . h2_{t-1} ----
        float accA[ROWS], accB[ROWS];   // two chains per row for ILP
#pragma unroll
        for (int r = 0; r < ROWS; ++r) { accA[r] = bias1; accB[r] = 0.0f; }
#pragma unroll
        for (int r = 0; r < ROWS; ++r) {
            const half8_t* hp1 = (const half8_t*)(&h1s[r][0]);
            const half8_t* hp2 = (const half8_t*)(&h2s[r][0]);
#pragma unroll
            for (int k = 0; k < HID / 8; ++k) {
                half8_t hv = hp1[k];
                accA[r] = dot2f(__builtin_shufflevector(hv, hv, 0, 1), wih1[4 * k + 0], accA[r]);
                accA[r] = dot2f(__builtin_shufflevector(hv, hv, 2, 3), wih1[4 * k + 1], accA[r]);
                accA[r] = dot2f(__builtin_shufflevector(hv, hv, 4, 5), wih1[4 * k + 2], accA[r]);
                accA[r] = dot2f(__builtin_shufflevector(hv, hv, 6, 7), wih1[4 * k + 3], accA[r]);
                half8_t hw = hp2[k];
                accB[r] = dot2f(__builtin_shufflevector(hw, hw, 0, 1), whh1[4 * k + 0], accB[r]);
                accB[r] = dot2f(__builtin_shufflevector(hw, hw, 2, 3), whh1[4 * k + 1], accB[r]);
                accB[r] = dot2f(__builtin_shufflevector(hw, hw, 4, 5), whh1[4 * k + 2], accB[r]);
                accB[r] = dot2f(__builtin_shufflevector(hw, hw, 6, 7), whh1[4 * k + 3], accB[r]);
            }
        }
        // prefetch next step's x slice (xs already consumed in phase 1)
        if (t < ROWS * 5 && s + 1 < SEQ)
            xs[t / 5][t % 5] = x[(size_t)(row0 + t / 5) * (SEQ * 5) + (s + 1) * 5 + (t % 5)];
#pragma unroll
        for (int r = 0; r < ROWS; ++r) gbuf[r][t] = accA[r] + accB[r];
        __syncthreads();

        // ---- phase 4: layer-1 pointwise update ----
        {
            float gi = gbuf[ur][uj];
            float gf = gbuf[ur][HID + uj];
            float gg = gbuf[ur][2 * HID + uj];
            float go = gbuf[ur][3 * HID + uj];
            float iv = sigm(gi), fv = sigm(gf), gv = tanh_fast(gg), ov = sigm(go);
            c2 = fmaf(fv, c2, iv * gv);
            h2v = ov * tanh_fast(c2);       // keep fp32 copy for epilogue
            h2s[ur][uj] = (half_t)h2v;
        }
        __syncthreads();
    }

    // ---- epilogue: out[row] = fc_b + sum_j fc_w[j] * h2_last[row][j] ----
    float p = fc_w[uj] * h2v;
#pragma unroll
    for (int off = 32; off > 0; off >>= 1) p += __shfl_down(p, off, 64);
    if ((t & 63) == 0) wpart[t >> 6] = p;
    __syncthreads();
    if (t < ROWS) out[row0 + t] = fc_b[0] + wpart[2 * t] + wpart[2 * t + 1];
}

extern "C" void kernel_launch(void* const* d_in, const int* in_sizes, int n_in,
                              void* d_out, int out_size, void* d_ws, size_t ws_size,
                              hipStream_t stream) {
    (void)in_sizes; (void)n_in; (void)d_ws; (void)ws_size; (void)out_size;
    const float* x     = (const float*)d_in[0];
    const float* w_ih0 = (const float*)d_in[1];
    const float* w_hh0 = (const float*)d_in[2];
    const float* b_ih0 = (const float*)d_in[3];
    const float* b_hh0 = (const float*)d_in[4];
    const float* w_ih1 = (const float*)d_in[5];
    const float* w_hh1 = (const float*)d_in[6];
    const float* b_ih1 = (const float*)d_in[7];
    const float* b_hh1 = (const float*)d_in[8];
    const float* fc_w  = (const float*)d_in[9];
    const float* fc_b  = (const float*)d_in[10];
    float* out = (float*)d_out;

    lstm2_fused<<<NBLK, NTHR, 0, stream>>>(x, w_ih0, w_hh0, b_ih0, b_hh0,
                                           w_ih1, w_hh1, b_ih1, b_hh1,
                                           fc_w, fc_b, out);
}

// Round 2
// 8950.521 us; speedup vs baseline: 6.0621x; 6.0621x over previous
//
#include <hip/hip_runtime.h>

// 2-layer LSTM (H=128) + FC, batch-parallel persistent kernel, round 2.
//
// Round-1 failure mode: 192 stationary weight VGPRs vs a 128-VGPR allocator
// cap -> full weight spill to scratch -> 133 GB HBM churn, VALUBusy 3%.
// Fix: 1024-thread blocks (16 waves -> 4 waves/SIMD co-resident -> 128-VGPR
// cap is structural) and K-SPLIT the gate dot across thread pairs:
//   thread t: gate row g = t>>1, K-half h = t&1.
//   Stationary weights: 3 matrices x 32 half2 = 96 VGPRs (fits with temps).
//   Partials combined with one __shfl_xor(.,1) (same wave).
// Two-layer fused pipeline, 2 barriers/step: phase P(s) computes layer-0
// gates for step s AND layer-1 gates for step s-1 (both read h1[s-1]);
// phase U(s) updates h1[s] (threads <512) and h2[s-1] (threads >=512).
// fp32 accumulation via v_dot2_f32_f16; h states fp16 in LDS (broadcast
// reads, 2 unique addrs/wave = conflict-free); c states fp32 in registers.

#define SEQ   512
#define BATCH 1024
#define HID   128
#define ROWS  4
#define NTHR  1024
#define NBLK  (BATCH / ROWS)

typedef _Float16 half_t;
typedef __attribute__((ext_vector_type(2))) _Float16 half2_t;
typedef __attribute__((ext_vector_type(8))) _Float16 half8_t;

__device__ __forceinline__ float dot2f(half2_t a, half2_t b, float c) {
    return __builtin_amdgcn_fdot2(a, b, c, false);
}
__device__ __forceinline__ float sigm(float x) {
    return 1.0f / (1.0f + __expf(-x));
}
__device__ __forceinline__ float tanh_fast(float x) {
    float e = __expf(2.0f * x);
    return 1.0f - 2.0f / (e + 1.0f);
}

__global__ void __launch_bounds__(NTHR)
__attribute__((amdgpu_waves_per_eu(4, 4)))
lstm2_fused(const float* __restrict__ x,
            const float* __restrict__ w_ih0, const float* __restrict__ w_hh0,
            const float* __restrict__ b_ih0, const float* __restrict__ b_hh0,
            const float* __restrict__ w_ih1, const float* __restrict__ w_hh1,
            const float* __restrict__ b_ih1, const float* __restrict__ b_hh1,
            const float* __restrict__ fc_w,  const float* __restrict__ fc_b,
            float* __restrict__ out)
{
    const int t    = threadIdx.x;
    const int g    = t >> 1;            // gate row 0..511 (PyTorch order i,f,g,o)
    const int h    = t & 1;             // K-half: elements [h*64, h*64+64)
    const int row0 = blockIdx.x * ROWS;

    __shared__ __align__(16) half_t h1s[ROWS][HID];
    __shared__ __align__(16) half_t h2s[ROWS][HID];
    __shared__ float gbuf0[ROWS][4 * HID];   // layer-0 pre-activations
    __shared__ float gbuf1[ROWS][4 * HID];   // layer-1 pre-activations
    __shared__ float xs[2][ROWS][5];         // double-buffered x slices
    __shared__ float wpart[16];              // epilogue wave partials

    // ---- stationary weights: fp32 -> fp16, 32 half2 per matrix = 96 VGPRs ----
    half2_t w0[32], w1[32], w2[32];
    {
        const float* p = w_hh0 + (size_t)g * HID + h * 64;
#pragma unroll
        for (int k = 0; k < 32; ++k) {
            float2 a = *(const float2*)(p + 2 * k);
            half2_t v; v[0] = (half_t)a.x; v[1] = (half_t)a.y; w0[k] = v;
        }
    }
    {
        const float* p = w_ih1 + (size_t)g * HID + h * 64;
#pragma unroll
        for (int k = 0; k < 32; ++k) {
            float2 a = *(const float2*)(p + 2 * k);
            half2_t v; v[0] = (half_t)a.x; v[1] = (half_t)a.y; w1[k] = v;
        }
    }
    {
        const float* p = w_hh1 + (size_t)g * HID + h * 64;
#pragma unroll
        for (int k = 0; k < 32; ++k) {
            float2 a = *(const float2*)(p + 2 * k);
            half2_t v; v[0] = (half_t)a.x; v[1] = (half_t)a.y; w2[k] = v;
        }
    }
    float wx[5];
#pragma unroll
    for (int d = 0; d < 5; ++d) wx[d] = w_ih0[g * 5 + d];
    const float bias0 = b_ih0[g] + b_hh0[g];
    const float bias1 = b_ih1[g] + b_hh1[g];

    // ---- update-phase mapping ----
    const bool lower = (t < 512);            // layer-0 update vs layer-1 update
    const int  ut = t & 511;
    const int  ur = ut >> 7;                 // batch row
    const int  uj = ut & (HID - 1);          // hidden index
    float cst = 0.0f, h2v = 0.0f;
    const float* gb   = lower ? &gbuf0[ur][0] : &gbuf1[ur][0];
    half_t*      hdst = lower ? &h1s[ur][0]  : &h2s[ur][0];

    if (t < ROWS * HID) { h1s[ur][uj] = (half_t)0.0f; h2s[ur][uj] = (half_t)0.0f; }
    if (t < ROWS * 5)
        xs[0][t / 5][t % 5] = x[(size_t)(row0 + t / 5) * (SEQ * 5) + (t % 5)];
    __syncthreads();

    for (int s = 0; s <= SEQ; ++s) {
        const int pb = s & 1;
        // ---- gate phase: layer-0 gates(s) + layer-1 gates(s-1) ----
#pragma unroll
        for (int r = 0; r < ROWS; ++r) {
            float xb = bias0;
#pragma unroll
            for (int d = 0; d < 5; ++d) xb = fmaf(wx[d], xs[pb][r][d], xb);
            float a0 = h ? 0.0f : xb;
            float a1 = h ? 0.0f : bias1;
            const half8_t* hp1 = (const half8_t*)(&h1s[r][h * 64]);
            const half8_t* hp2 = (const half8_t*)(&h2s[r][h * 64]);
#pragma unroll
            for (int k = 0; k < 8; ++k) {
                half8_t v = hp1[k];    // 2 unique addrs/wave -> free broadcast
                half2_t v0 = __builtin_shufflevector(v, v, 0, 1);
                half2_t v1 = __builtin_shufflevector(v, v, 2, 3);
                half2_t v2 = __builtin_shufflevector(v, v, 4, 5);
                half2_t v3 = __builtin_shufflevector(v, v, 6, 7);
                a0 = dot2f(v0, w0[4 * k + 0], a0);  a1 = dot2f(v0, w1[4 * k + 0], a1);
                a0 = dot2f(v1, w0[4 * k + 1], a0);  a1 = dot2f(v1, w1[4 * k + 1], a1);
                a0 = dot2f(v2, w0[4 * k + 2], a0);  a1 = dot2f(v2, w1[4 * k + 2], a1);
                a0 = dot2f(v3, w0[4 * k + 3], a0);  a1 = dot2f(v3, w1[4 * k + 3], a1);
            }
#pragma unroll
            for (int k = 0; k < 8; ++k) {
                half8_t v = hp2[k];
                a1 = dot2f(__builtin_shufflevector(v, v, 0, 1), w2[4 * k + 0], a1);
                a1 = dot2f(__builtin_shufflevector(v, v, 2, 3), w2[4 * k + 1], a1);
                a1 = dot2f(__builtin_shufflevector(v, v, 4, 5), w2[4 * k + 2], a1);
                a1 = dot2f(__builtin_shufflevector(v, v, 6, 7), w2[4 * k + 3], a1);
            }
            a0 += __shfl_xor(a0, 1);
            a1 += __shfl_xor(a1, 1);
            if (h == 0) gbuf0[r][g] = a0;   // even lane: layer-0 gate
            else        gbuf1[r][g] = a1;   // odd lane: layer-1 gate
        }
        // prefetch x for next step's layer-0 phase
        if (t < ROWS * 5) {
            int xi = (s + 1 < SEQ) ? (s + 1) : (SEQ - 1);
            xs[(s + 1) & 1][t / 5][t % 5] =
                x[(size_t)(row0 + t / 5) * (SEQ * 5) + xi * 5 + (t % 5)];
        }
        __syncthreads();

        // ---- update phase: h1[s] (lower), h2[s-1] (upper, skip at s==0) ----
        if (lower | (s > 0)) {
            float gi = gb[uj];
            float gf = gb[HID + uj];
            float gg = gb[2 * HID + uj];
            float go = gb[3 * HID + uj];
            float iv = sigm(gi), fv = sigm(gf), gv = tanh_fast(gg), ov = sigm(go);
            cst = fmaf(fv, cst, iv * gv);
            float hv_ = ov * tanh_fast(cst);
            hdst[uj] = (half_t)hv_;
            h2v = hv_;                      // meaningful for upper threads only
        }
        __syncthreads();
    }

    // ---- epilogue: out[row] = fc_b + sum_j fc_w[j] * h2[511][row][j] ----
    float p = (t >= 512) ? fc_w[uj] * h2v : 0.0f;
#pragma unroll
    for (int off = 32; off > 0; off >>= 1) p += __shfl_xor(p, off);
    if ((t & 63) == 0) wpart[t >> 6] = p;
    __syncthreads();
    if (t < ROWS) out[row0 + t] = fc_b[0] + wpart[8 + 2 * t] + wpart[8 + 2 * t + 1];
}

extern "C" void kernel_launch(void* const* d_in, const int* in_sizes, int n_in,
                              void* d_out, int out_size, void* d_ws, size_t ws_size,
                              hipStream_t stream) {
    (void)in_sizes; (void)n_in; (void)d_ws; (void)ws_size; (void)out_size;
    const float* x     = (const float*)d_in[0];
    const float* w_ih0 = (const float*)d_in[1];
    const float* w_hh0 = (const float*)d_in[2];
    const float* b_ih0 = (const float*)d_in[3];
    const float* b_hh0 = (const float*)d_in[4];
    const float* w_ih1 = (const float*)d_in[5];
    const float* w_hh1 = (const float*)d_in[6];
    const float* b_ih1 = (const float*)d_in[7];
    const float* b_hh1 = (const float*)d_in[8];
    const float* fc_w  = (const float*)d_in[9];
    const float* fc_b  = (const float*)d_in[10];
    float* out = (float*)d_out;

    lstm2_fused<<<NBLK, NTHR, 0, stream>>>(x, w_ih0, w_hh0, b_ih0, b_hh0,
                                           w_ih1, w_hh1, b_ih1, b_hh1,
                                           fc_w, fc_b, out);
}

// Round 3
// 2447.881 us; speedup vs baseline: 22.1658x; 3.6564x over previous
//
#include <hip/hip_runtime.h>

// 2-layer LSTM (H=128) + FC, batch-parallel persistent kernel, round 3.
//
// Round-2 failure: compiler saw 18.9 KB LDS -> "2 blocks/CU possible" ->
// targeted 8 waves/EU -> 64-VGPR budget -> spilled all weight registers
// (WRITE_SIZE 189 MB, VALUBusy 20%). Grid is 1 block/CU, so that occupancy
// never even materialized.
// Fix: pad static LDS past 80 KB so max occupancy AT COMPILE TIME is
// 1 block/CU = 8 waves/CU = 2 waves/EU -> VGPR budget 256, structurally.
// Spend the budget on 2 gate rows per thread (6*32 half2 = 192 weight VGPRs):
// doubles dot2s per LDS h-byte, halving the broadcast-LDS bottleneck.
//
// Mapping: thread t (of 512): gate pair ga=2*(t>>1), gb=ga+1; K-half h=t&1.
// Partner t^1 (same wave) holds the other K-half; one __shfl_xor(.,1)
// combines. Even lane writes layer-0 gates, odd lane layer-1 gates.
// Two-layer fused pipeline (lag 1), 2 barriers/step. fp32 accumulation via
// v_dot2_f32_f16; h states fp16 in LDS; c states fp32 in registers.

#define SEQ   512
#define BATCH 1024
#define HID   128
#define ROWS  4
#define NTHR  512
#define NBLK  (BATCH / ROWS)

typedef _Float16 half_t;
typedef __attribute__((ext_vector_type(2))) _Float16 half2_t;
typedef __attribute__((ext_vector_type(8))) _Float16 half8_t;

__device__ __forceinline__ float dot2f(half2_t a, half2_t b, float c) {
    return __builtin_amdgcn_fdot2(a, b, c, false);
}
__device__ __forceinline__ float sigm(float x) {
    return 1.0f / (1.0f + __expf(-x));
}
__device__ __forceinline__ float tanh_fast(float x) {
    float e = __expf(2.0f * x);
    return 1.0f - 2.0f / (e + 1.0f);
}

__global__ void __launch_bounds__(NTHR)
__attribute__((amdgpu_waves_per_eu(2)))
lstm2_fused(const float* __restrict__ x,
            const float* __restrict__ w_ih0, const float* __restrict__ w_hh0,
            const float* __restrict__ b_ih0, const float* __restrict__ b_hh0,
            const float* __restrict__ w_ih1, const float* __restrict__ w_hh1,
            const float* __restrict__ b_ih1, const float* __restrict__ b_hh1,
            const float* __restrict__ fc_w,  const float* __restrict__ fc_b,
            float* __restrict__ out)
{
    const int t    = threadIdx.x;
    const int h    = t & 1;              // K-half: elements [h*64, h*64+64)
    const int ga   = (t >> 1) * 2;       // first owned gate row
    const int gb   = ga + 1;             // second owned gate row
    const int row0 = blockIdx.x * ROWS;

    __shared__ __align__(16) half_t h1s[ROWS][HID];
    __shared__ __align__(16) half_t h2s[ROWS][HID];
    __shared__ float gbuf0[ROWS][4 * HID];   // layer-0 pre-activations
    __shared__ float gbuf1[ROWS][4 * HID];   // layer-1 pre-activations
    __shared__ float xs[2][ROWS][5];         // double-buffered x slices
    // Occupancy pad: total static LDS ~92 KB > 80 KB => max 1 block/CU at
    // compile time => 2 waves/EU => 256-VGPR budget. Also epilogue scratch.
    __shared__ float ldspad[18432];

    // ---- stationary weights: fp32 -> fp16, 6 x 32 half2 = 192 VGPRs ----
    half2_t w0a[32], w0b[32], w1a[32], w1b[32], w2a[32], w2b[32];
#define LOADW(dst, src, grow)                                            \
    {                                                                    \
        const float* p_ = (src) + (size_t)(grow) * HID + h * 64;         \
        _Pragma("unroll")                                                \
        for (int k_ = 0; k_ < 32; ++k_) {                                \
            float2 a_ = *(const float2*)(p_ + 2 * k_);                   \
            half2_t v_; v_[0] = (half_t)a_.x; v_[1] = (half_t)a_.y;      \
            dst[k_] = v_;                                                \
        }                                                                \
    }
    LOADW(w0a, w_hh0, ga) LOADW(w0b, w_hh0, gb)
    LOADW(w1a, w_ih1, ga) LOADW(w1b, w_ih1, gb)
    LOADW(w2a, w_hh1, ga) LOADW(w2b, w_hh1, gb)
#undef LOADW

    float wxa[5], wxb[5];
#pragma unroll
    for (int d = 0; d < 5; ++d) { wxa[d] = w_ih0[ga * 5 + d]; wxb[d] = w_ih0[gb * 5 + d]; }
    const float bias0a = b_ih0[ga] + b_hh0[ga];
    const float bias0b = b_ih0[gb] + b_hh0[gb];
    const float bias1a = b_ih1[ga] + b_hh1[ga];
    const float bias1b = b_ih1[gb] + b_hh1[gb];

    // ---- update mapping: thread t handles (row ur, hidden uj), BOTH layers ----
    const int ur = t >> 7;
    const int uj = t & (HID - 1);
    float c1 = 0.0f, c2 = 0.0f, h2v = 0.0f;

    h1s[ur][uj] = (half_t)0.0f;
    h2s[ur][uj] = (half_t)0.0f;
    if (t < ROWS * 5)
        xs[0][t / 5][t % 5] = x[(size_t)(row0 + t / 5) * (SEQ * 5) + (t % 5)];
    __syncthreads();

    for (int s = 0; s <= SEQ; ++s) {
        const int pb = s & 1;
        // ---- gate phase: layer-0 gates(s) + layer-1 gates(s-1) ----
#pragma unroll
        for (int r = 0; r < ROWS; ++r) {
            float xba = bias0a, xbb = bias0b;
#pragma unroll
            for (int d = 0; d < 5; ++d) {
                float xv = xs[pb][r][d];
                xba = fmaf(wxa[d], xv, xba);
                xbb = fmaf(wxb[d], xv, xbb);
            }
            float a0a = h ? 0.0f : xba;
            float a0b = h ? 0.0f : xbb;
            float a1a = h ? 0.0f : bias1a;
            float a1b = h ? 0.0f : bias1b;
            const half8_t* hp1 = (const half8_t*)(&h1s[r][h * 64]);
            const half8_t* hp2 = (const half8_t*)(&h2s[r][h * 64]);
#pragma unroll
            for (int k = 0; k < 8; ++k) {
                half8_t v = hp1[k];   // 2 unique addrs/wave -> broadcast read
#pragma unroll
                for (int j = 0; j < 4; ++j) {
                    half2_t vv = __builtin_shufflevector(v, v, 0, 1);
                    if (j == 1) vv = __builtin_shufflevector(v, v, 2, 3);
                    if (j == 2) vv = __builtin_shufflevector(v, v, 4, 5);
                    if (j == 3) vv = __builtin_shufflevector(v, v, 6, 7);
                    a0a = dot2f(vv, w0a[4 * k + j], a0a);
                    a0b = dot2f(vv, w0b[4 * k + j], a0b);
                    a1a = dot2f(vv, w1a[4 * k + j], a1a);
                    a1b = dot2f(vv, w1b[4 * k + j], a1b);
                }
                half8_t u = hp2[k];
#pragma unroll
                for (int j = 0; j < 4; ++j) {
                    half2_t uu = __builtin_shufflevector(u, u, 0, 1);
                    if (j == 1) uu = __builtin_shufflevector(u, u, 2, 3);
                    if (j == 2) uu = __builtin_shufflevector(u, u, 4, 5);
                    if (j == 3) uu = __builtin_shufflevector(u, u, 6, 7);
                    a1a = dot2f(uu, w2a[4 * k + j], a1a);
                    a1b = dot2f(uu, w2b[4 * k + j], a1b);
                }
            }
            a0a += __shfl_xor(a0a, 1);
            a0b += __shfl_xor(a0b, 1);
            a1a += __shfl_xor(a1a, 1);
            a1b += __shfl_xor(a1b, 1);
            if (h == 0) *(float2*)&gbuf0[r][ga] = make_float2(a0a, a0b);
            else        *(float2*)&gbuf1[r][ga] = make_float2(a1a, a1b);
        }
        // prefetch next step's x slice
        if (t < ROWS * 5) {
            int xi = (s + 1 < SEQ) ? (s + 1) : (SEQ - 1);
            xs[(s + 1) & 1][t / 5][t % 5] =
                x[(size_t)(row0 + t / 5) * (SEQ * 5) + xi * 5 + (t % 5)];
        }
        __syncthreads();

        // ---- update phase: h1[s] and h2[s-1] (both in this thread) ----
        {
            float gi = gbuf0[ur][uj];
            float gf = gbuf0[ur][HID + uj];
            float gg = gbuf0[ur][2 * HID + uj];
            float go = gbuf0[ur][3 * HID + uj];
            float iv = sigm(gi), fv = sigm(gf), gv = tanh_fast(gg), ov = sigm(go);
            c1 = fmaf(fv, c1, iv * gv);
            h1s[ur][uj] = (half_t)(ov * tanh_fast(c1));
        }
        if (s > 0) {
            float gi = gbuf1[ur][uj];
            float gf = gbuf1[ur][HID + uj];
            float gg = gbuf1[ur][2 * HID + uj];
            float go = gbuf1[ur][3 * HID + uj];
            float iv = sigm(gi), fv = sigm(gf), gv = tanh_fast(gg), ov = sigm(go);
            c2 = fmaf(fv, c2, iv * gv);
            h2v = ov * tanh_fast(c2);
            h2s[ur][uj] = (half_t)h2v;
        }
        __syncthreads();
    }

    // ---- epilogue: out[row] = fc_b + sum_j fc_w[j] * h2[511][row][j] ----
    float p = fc_w[uj] * h2v;
#pragma unroll
    for (int off = 32; off > 0; off >>= 1) p += __shfl_xor(p, off);
    if ((t & 63) == 0) ldspad[t >> 6] = p;
    __syncthreads();
    if (t < ROWS) out[row0 + t] = fc_b[0] + ldspad[2 * t] + ldspad[2 * t + 1];
}

extern "C" void kernel_launch(void* const* d_in, const int* in_sizes, int n_in,
                              void* d_out, int out_size, void* d_ws, size_t ws_size,
                              hipStream_t stream) {
    (void)in_sizes; (void)n_in; (void)d_ws; (void)ws_size; (void)out_size;
    const float* x     = (const float*)d_in[0];
    const float* w_ih0 = (const float*)d_in[1];
    const float* w_hh0 = (const float*)d_in[2];
    const float* b_ih0 = (const float*)d_in[3];
    const float* b_hh0 = (const float*)d_in[4];
    const float* w_ih1 = (const float*)d_in[5];
    const float* w_hh1 = (const float*)d_in[6];
    const float* b_ih1 = (const float*)d_in[7];
    const float* b_hh1 = (const float*)d_in[8];
    const float* fc_w  = (const float*)d_in[9];
    const float* fc_b  = (const float*)d_in[10];
    float* out = (float*)d_out;

    lstm2_fused<<<NBLK, NTHR, 0, stream>>>(x, w_ih0, w_hh0, b_ih0, b_hh0,
                                           w_ih1, w_hh1, b_ih1, b_hh1,
                                           fc_w, fc_b, out);
}